// Round 10
// baseline (107.968 us; speedup 1.0000x reference)
//
#include <hip/hip_runtime.h>

#define E_DIM 1024
#define D_DIM 128
#define T_DIM 4096

typedef unsigned short u16;
typedef u16 u16x8 __attribute__((ext_vector_type(8)));
typedef u16 u16x4 __attribute__((ext_vector_type(4)));
typedef __bf16 bf16x8 __attribute__((ext_vector_type(8)));
typedef float f32x4 __attribute__((ext_vector_type(4)));

__device__ __forceinline__ u16 cvt_bf16(float f) {
    unsigned u = __float_as_uint(f);
    u += 0x7FFF + ((u >> 16) & 1);   // RNE
    return (u16)(u >> 16);
}

__device__ __forceinline__ float bf2f(u16 v) {
    return __uint_as_float(((unsigned)v) << 16);
}

__device__ __forceinline__ f32x4 mfma16(u16x8 a, u16x8 b, f32x4 c) {
    return __builtin_amdgcn_mfma_f32_16x16x32_bf16(
        __builtin_bit_cast(bf16x8, a), __builtin_bit_cast(bf16x8, b), c, 0, 0, 0);
}

// async global->LDS DMA, 16B per lane; lds ptr must be wave-uniform base
__device__ __forceinline__ void gld_lds16(const void* g, void* l) {
    __builtin_amdgcn_global_load_lds(
        (const __attribute__((address_space(1))) unsigned int*)g,
        (__attribute__((address_space(3))) unsigned int*)l, 16, 0, 0);
}

// ---------- prep: transpose weights to [out][in], cast to bf16 ----------
__global__ void prep_kernel(const float* __restrict__ Wk, const float* __restrict__ Wq,
                            const float* __restrict__ Wv, const float* __restrict__ Wp,
                            u16* __restrict__ Wqt, u16* __restrict__ Wkt,
                            u16* __restrict__ Wvt, u16* __restrict__ Wpt) {
    int tid = blockIdx.x * 256 + threadIdx.x;
    const int WT = 128 * 1024;
    if (tid < 3 * WT) {
        int w = tid / WT;
        int r = tid - w * WT;
        int n = r >> 10, k = r & 1023;
        const float* W = (w == 0) ? Wq : (w == 1) ? Wk : Wv;
        u16* Wt = (w == 0) ? Wqt : (w == 1) ? Wkt : Wvt;
        Wt[r] = cvt_bf16(W[k * 128 + n]);
    } else {
        int r = tid - 3 * WT;
        if (r < 128 * 128) {
            int n = r >> 7, k = r & 127;
            Wpt[r] = cvt_bf16(Wp[k * 128 + n]);
        }
    }
}

// ---------- fused QKV projection v3: counted-vmcnt pipeline ----------
// 512 blocks: rg = bx>>1 (64 rows), cgrp = bx&1 (192 of 384 cols).
// Static dbuf: bufA (even k-tiles) @0, bufB (odd) @12288. Per half-iter:
// cvt(x) -> stage next W (3 gld_lds) -> issue next x (4 loads) -> 12 MFMA ->
// s_waitcnt vmcnt(4) lgkmcnt(0) (x loads stay in flight) -> raw s_barrier.
__global__ __launch_bounds__(256) void qkv_kernel(
        const float* __restrict__ x,
        const u16* __restrict__ Wqt, const u16* __restrict__ Wkt, const u16* __restrict__ Wvt,
        u16* __restrict__ qb, u16* __restrict__ kb, u16* __restrict__ vT) {
    __shared__ __align__(16) char smem[24576];   // 2 x 12288 (192 rows x 64B)

    const int t = threadIdx.x;
    const int w = t >> 6;
    const int lane = t & 63;
    const int lr = lane & 15;
    const int lg = lane >> 4;
    const int m = w & 1;           // row half (32 rows)
    const int n = w >> 1;          // col half (96 cols)
    const int rg = blockIdx.x >> 1;
    const int cgrp = blockIdx.x & 1;
    const int r0 = rg * 64;

    // stage 192x32 W tile (k0) into buffer BUF, slot-rotated (conflict-free reads)
    #define STAGE_W(K0, BUF) do {                                                 \
        char* wB_ = smem + (BUF) * 12288;                                         \
        _Pragma("unroll")                                                         \
        for (int c2 = 0; c2 < 3; ++c2) {                                          \
            const int rl_ = c2 * 64 + (t >> 2);                                   \
            const int gn_ = cgrp * 192 + rl_;                                     \
            const u16* W_ = (gn_ < 128) ? Wqt : (gn_ < 256) ? Wkt : Wvt;          \
            const int s_ = ((t & 3) - (rl_ >> 1)) & 3;                            \
            gld_lds16(W_ + (size_t)(gn_ & 127) * E_DIM + (K0) + 8 * s_,           \
                      wB_ + c2 * 4096 + t * 16);                                  \
        }                                                                         \
    } while (0)

    const float* xp0 = x + (size_t)(r0 + 32 * m + lr) * E_DIM + lg * 8;
    const float* xp1 = xp0 + 16 * E_DIM;

    float4 xa[4], xb[4];
    #define XLOAD(arr, K0) do {                                                   \
        arr[0] = *(const float4*)(xp0 + (K0));                                    \
        arr[1] = *(const float4*)(xp0 + (K0) + 4);                                \
        arr[2] = *(const float4*)(xp1 + (K0));                                    \
        arr[3] = *(const float4*)(xp1 + (K0) + 4);                                \
    } while (0)

    #define CVT_AV(av, arr) do {                                                  \
        _Pragma("unroll")                                                         \
        for (int i = 0; i < 2; ++i) {                                             \
            av[i][0] = cvt_bf16(arr[2*i].x);   av[i][1] = cvt_bf16(arr[2*i].y);   \
            av[i][2] = cvt_bf16(arr[2*i].z);   av[i][3] = cvt_bf16(arr[2*i].w);   \
            av[i][4] = cvt_bf16(arr[2*i+1].x); av[i][5] = cvt_bf16(arr[2*i+1].y); \
            av[i][6] = cvt_bf16(arr[2*i+1].z); av[i][7] = cvt_bf16(arr[2*i+1].w); \
        }                                                                         \
    } while (0)

    #define MFMA_PHASE(BUF, av) do {                                              \
        char* wB = smem + (BUF) * 12288;                                          \
        __builtin_amdgcn_s_setprio(1);                                            \
        _Pragma("unroll")                                                         \
        for (int nt = 0; nt < 6; ++nt) {                                          \
            const int ln = n * 96 + nt * 16 + lr;                                 \
            u16x8 bv = *(u16x8*)(wB + ln * 64 + (((lg + (ln >> 1)) & 3) << 4));   \
            acc[0][nt] = mfma16(av[0], bv, acc[0][nt]);                           \
            acc[1][nt] = mfma16(av[1], bv, acc[1][nt]);                           \
        }                                                                         \
        __builtin_amdgcn_s_setprio(0);                                            \
    } while (0)

    f32x4 acc[2][6];
    #pragma unroll
    for (int i = 0; i < 2; ++i)
        #pragma unroll
        for (int j = 0; j < 6; ++j) acc[i][j] = f32x4{0.f, 0.f, 0.f, 0.f};

    // prologue: x for tiles 0,1 in flight; W tile 0 staged
    XLOAD(xa, 0);
    XLOAD(xb, 32);
    STAGE_W(0, 0);
    asm volatile("s_waitcnt vmcnt(0)" ::: "memory");
    __builtin_amdgcn_s_barrier();

    for (int kk = 0; kk < 16; ++kk) {
        const int k0 = kk * 64;
        const bool more = (kk < 15);
        // ---- half A: tile k0 from bufA ----
        u16x8 avA[2];
        CVT_AV(avA, xa);
        __builtin_amdgcn_sched_barrier(0);
        STAGE_W(k0 + 32, 1);                       // k0+32 <= 992 always
        __builtin_amdgcn_sched_barrier(0);
        if (more) XLOAD(xa, k0 + 64);
        __builtin_amdgcn_sched_barrier(0);
        MFMA_PHASE(0, avA);
        if (more) asm volatile("s_waitcnt vmcnt(4) lgkmcnt(0)" ::: "memory");
        else      asm volatile("s_waitcnt vmcnt(0) lgkmcnt(0)" ::: "memory");
        __builtin_amdgcn_s_barrier();
        // ---- half B: tile k0+32 from bufB ----
        u16x8 avB[2];
        CVT_AV(avB, xb);
        __builtin_amdgcn_sched_barrier(0);
        if (more) {
            STAGE_W(k0 + 64, 0);
            __builtin_amdgcn_sched_barrier(0);
            XLOAD(xb, k0 + 96);                    // k0+96 <= 1056? kk<15 -> <=1056-64=992+... (kk=14: 992) OK
        }
        __builtin_amdgcn_sched_barrier(0);
        MFMA_PHASE(1, avB);
        if (more) asm volatile("s_waitcnt vmcnt(4) lgkmcnt(0)" ::: "memory");
        else      asm volatile("s_waitcnt vmcnt(0) lgkmcnt(0)" ::: "memory");
        __builtin_amdgcn_s_barrier();
    }
    #undef STAGE_W
    #undef XLOAD
    #undef CVT_AV
    #undef MFMA_PHASE

    // epilogue: D layout col=lane&15, row=4*(lane>>4)+reg
    const int bb = r0 >> 12;
    #pragma unroll
    for (int i = 0; i < 2; ++i) {
        const int row0 = r0 + 32 * m + 16 * i + 4 * lg;
        const int tt0 = row0 & 4095;
        #pragma unroll
        for (int nt = 0; nt < 6; ++nt) {
            const int col_g = cgrp * 192 + n * 96 + nt * 16 + lr;
            const int j = col_g >> 7;
            const int colw = col_g & 127;
            if (j < 2) {
                u16* outb = (j == 0) ? qb : kb;
                #pragma unroll
                for (int reg = 0; reg < 4; ++reg)
                    outb[(size_t)(row0 + reg) * D_DIM + colw] = cvt_bf16(acc[i][nt][reg]);
            } else {
                u16x4 pv;
                #pragma unroll
                for (int reg = 0; reg < 4; ++reg) pv[reg] = cvt_bf16(acc[i][nt][reg]);
                *(u16x4*)&vT[((size_t)(bb * 128 + colw)) * T_DIM + tt0] = pv;
            }
        }
    }
}

// ---------- flash attention (causal): QBLK=128, 8 waves, K/V LDS dbuf, O^T accum ----------
__global__ __launch_bounds__(512) void attn_kernel(
        const u16* __restrict__ qb, const u16* __restrict__ kb, const u16* __restrict__ vT,
        u16* __restrict__ Opart, float* __restrict__ ml, int SPLIT) {
    const int g = blockIdx.x;
    const int b = blockIdx.y;
    int i, c;
    if (SPLIT) {
        int k = 0;
        while (2 * (k + 1) * (k + 2) <= g) ++k;
        const int off = g - 2 * k * (k + 1);
        const int iband = off / (k + 1);
        c = off - iband * (k + 1);
        i = 4 * k + iband;
    } else { i = g; c = 0; }

    const int q0 = i * 128;
    const int kv_beg = c * 512;
    const int kv_end = SPLIT ? min(q0 + 128, kv_beg + 512) : (q0 + 128);
    const int slot = b * gridDim.x + g;

    __shared__ __align__(16) char smem[81920];

    const int t = threadIdx.x;
    const int w = t >> 6;          // 0..7
    const int lane = t & 63;
    const int lr = lane & 15;
    const int lg = lane >> 4;
    const size_t base = (size_t)b * T_DIM * D_DIM;

    // Q fragments direct from global (L2-resident)
    u16x8 qf[4];
    {
        const u16* qp = qb + base + (size_t)(q0 + 16 * w + lr) * D_DIM + lg * 8;
        #pragma unroll
        for (int dk = 0; dk < 4; ++dk) qf[dk] = *(const u16x8*)(qp + dk * 32);
    }

    const char* kpb = (const char*)(kb + base);
    const char* vpb = (const char*)(vT + (size_t)b * D_DIM * T_DIM);
    const int key = (lr & 7) << 4;

    #define STAGE(S0, BUF) do {                                                   \
        char* kB_ = smem + (BUF) * 16384;                                         \
        char* vB_ = smem + 32768 + (BUF) * 16384;                                 \
        const int wbase_ = (t >> 6) * 1024;                                       \
        _Pragma("unroll")                                                         \
        for (int c2 = 0; c2 < 2; ++c2) {                                          \
            const int krow_ = c2 * 32 + (t >> 4);                                 \
            gld_lds16(kpb + (size_t)((S0) + krow_) * 256 +                        \
                      (((t & 15) * 16) ^ ((krow_ & 7) * 16)),                     \
                      kB_ + c2 * 8192 + wbase_);                                  \
            const int vrow_ = c2 * 64 + (t >> 3);                                 \
            gld_lds16(vpb + (size_t)vrow_ * (T_DIM * 2) + (size_t)(S0) * 2 +      \
                      (((t & 7) * 16) ^ ((vrow_ & 7) * 16)),                      \
                      vB_ + c2 * 8192 + wbase_);                                  \
        }                                                                         \
    } while (0)

    f32x4 oacc[8];
    #pragma unroll
    for (int nn = 0; nn < 8; ++nn) oacc[nn] = f32x4{0.f, 0.f, 0.f, 0.f};
    float m_run = -1e30f, l_run = 0.f;
    const float scale2 = 0.12752048520120164f;  // log2(e)/sqrt(128)
    const int qrow = q0 + 16 * w + lr;          // this lane's q row

    STAGE(kv_beg, 0);
    asm volatile("s_waitcnt vmcnt(0)" ::: "memory");
    __syncthreads();

    int buf = 0;
    for (int s0 = kv_beg; s0 < kv_end; s0 += 64) {
        if (s0 + 64 < kv_end) STAGE(s0 + 64, buf ^ 1);   // async prefetch

        char* kB  = smem + buf * 16384;
        char* vB  = smem + 32768 + buf * 16384;
        char* psB = smem + 65536 + w * 2048;

        // S^T = K Q^T : lane (lr,lg) holds S[s=s0+16nt+4lg+r][q=16w+lr]
        f32x4 sacc[4];
        #pragma unroll
        for (int nn = 0; nn < 4; ++nn) sacc[nn] = f32x4{0.f, 0.f, 0.f, 0.f};
        __builtin_amdgcn_s_setprio(1);
        #pragma unroll
        for (int dk = 0; dk < 4; ++dk) {
            #pragma unroll
            for (int nt = 0; nt < 4; ++nt) {
                u16x8 kfr = *(u16x8*)(kB + (nt * 16 + lr) * 256 + ((dk * 64 + lg * 16) ^ key));
                sacc[nt] = mfma16(kfr, qf[dk], sacc[nt]);
            }
        }
        __builtin_amdgcn_s_setprio(0);

        // scale + causal mask
        float sv[4][4];
        const bool need_mask = (s0 + 63 > q0 + 16 * w);
        #pragma unroll
        for (int nt = 0; nt < 4; ++nt) {
            #pragma unroll
            for (int r = 0; r < 4; ++r) {
                float v = sacc[nt][r] * scale2;
                if (need_mask && (s0 + nt * 16 + 4 * lg + r) > qrow) v = -1e30f;
                sv[nt][r] = v;
            }
        }

        // softmax: in-register over 16 + 2-level cross-lg reduce (lane-local row)
        float tmax = sv[0][0];
        #pragma unroll
        for (int nt = 0; nt < 4; ++nt)
            #pragma unroll
            for (int r = 0; r < 4; ++r) tmax = fmaxf(tmax, sv[nt][r]);
        tmax = fmaxf(tmax, __shfl_xor(tmax, 16));
        tmax = fmaxf(tmax, __shfl_xor(tmax, 32));
        float m_new = fmaxf(m_run, tmax);
        float rsc = __builtin_amdgcn_exp2f(m_run - m_new);
        m_run = m_new;
        float tsum = 0.f;
        #pragma unroll
        for (int nt = 0; nt < 4; ++nt)
            #pragma unroll
            for (int r = 0; r < 4; ++r) {
                sv[nt][r] = __builtin_amdgcn_exp2f(sv[nt][r] - m_new);
                tsum += sv[nt][r];
            }
        tsum += __shfl_xor(tsum, 16);
        tsum += __shfl_xor(tsum, 32);
        l_run = l_run * rsc + tsum;

        // rescale O^T accumulator: factor lane-local (output col q = lr)
        #pragma unroll
        for (int nt = 0; nt < 8; ++nt)
            #pragma unroll
            for (int r = 0; r < 4; ++r) oacc[nt][r] *= rsc;

        // P -> wave-private swizzled Ps: lane writes row q=lr, cols 16nt+4lg+{0..3}
        #pragma unroll
        for (int nt = 0; nt < 4; ++nt) {
            u16x4 pv4;
            #pragma unroll
            for (int r = 0; r < 4; ++r) pv4[r] = cvt_bf16(sv[nt][r]);
            *(u16x4*)(psB + lr * 128 + ((nt * 32 + lg * 8) ^ key)) = pv4;
        }

        // P^T fragments: lane (lr,lg) reads P[q=lr][s=8lg+e] (+32)
        u16x8 pA0 = *(u16x8*)(psB + lr * 128 + ((lg * 16) ^ key));
        u16x8 pA1 = *(u16x8*)(psB + lr * 128 + ((64 + lg * 16) ^ key));

        // O^T += V^T P^T  (A = V^T fragment from LDS, B = P^T fragment)
        __builtin_amdgcn_s_setprio(1);
        #pragma unroll
        for (int nt = 0; nt < 8; ++nt) {
            u16x8 bv0 = *(u16x8*)(vB + (nt * 16 + lr) * 128 + ((lg * 16) ^ key));
            oacc[nt] = mfma16(bv0, pA0, oacc[nt]);
            u16x8 bv1 = *(u16x8*)(vB + (nt * 16 + lr) * 128 + ((64 + lg * 16) ^ key));
            oacc[nt] = mfma16(bv1, pA1, oacc[nt]);
        }
        __builtin_amdgcn_s_setprio(0);

        asm volatile("s_waitcnt vmcnt(0)" ::: "memory");   // drain prefetch
        __syncthreads();
        buf ^= 1;
    }
    #undef STAGE

    // m,l per q row (lane lr of lg==0 owns q=16w+lr)
    if (lg == 0) {
        int row = 16 * w + lr;
        ml[(size_t)(slot * 128 + row) * 2]     = m_run;
        ml[(size_t)(slot * 128 + row) * 2 + 1] = l_run;
    }

    // normalize (lane-local) and bounce O through LDS (reuse Kbuf, 128x256B swz)
    const float invl = 1.f / l_run;
    const int orw = 16 * w + lr;
    #pragma unroll
    for (int nt = 0; nt < 8; ++nt) {
        u16x4 ov;
        #pragma unroll
        for (int r = 0; r < 4; ++r) ov[r] = cvt_bf16(oacc[nt][r] * invl);
        *(u16x4*)(smem + orw * 256 + ((32 * nt + 8 * lg) ^ ((orw & 7) << 4))) = ov;
    }
    __syncthreads();
    u16* op = Opart + (size_t)slot * 16384;
    const int orow = t >> 2;
    const int oseg = t & 3;
    #pragma unroll
    for (int j = 0; j < 4; ++j) {
        u16x8 vv = *(u16x8*)(smem + orow * 256 + ((oseg * 64 + j * 16) ^ ((orow & 7) << 4)));
        *(u16x8*)(op + orow * 128 + oseg * 32 + j * 8) = vv;
    }
}

// ---------- combine partials + fused output projection ----------
__global__ __launch_bounds__(256) void combine_kernel(
        const u16* __restrict__ Opart, const float* __restrict__ ml,
        const u16* __restrict__ Wpt, float* __restrict__ out,
        int SPLIT, int NSLOT) {
    const int io = blockIdx.x;          // 64-row output tile, 0..63
    const int b = blockIdx.y;
    const int i = io >> 1;              // 128-row attn tile
    const int half = io & 1;
    int NC, g0;
    if (SPLIT) {
        int k = i >> 2;
        NC = k + 1;
        g0 = 2 * k * (k + 1) + (i & 3) * (k + 1);
    } else { NC = 1; g0 = i; }
    const int slot0 = b * NSLOT + g0;

    __shared__ u16 Os[64][136];
    const int t = threadIdx.x;
    const int row = t >> 2, seg = (t & 3) * 32;
    const int row_in = half * 64 + row;

    float m_fin = -1e30f;
    for (int c = 0; c < NC; ++c)
        m_fin = fmaxf(m_fin, ml[(size_t)((slot0 + c) * 128 + row_in) * 2]);

    float acc[32];
    #pragma unroll
    for (int j = 0; j < 32; ++j) acc[j] = 0.f;
    float l_fin = 0.f;
    for (int c = 0; c < NC; ++c) {
        float mcv = ml[(size_t)((slot0 + c) * 128 + row_in) * 2];
        float lcv = ml[(size_t)((slot0 + c) * 128 + row_in) * 2 + 1];
        float wgt = __builtin_amdgcn_exp2f(mcv - m_fin) * lcv;
        l_fin += wgt;
        const u16* opc = Opart + (size_t)(slot0 + c) * 16384 + row_in * 128 + seg;
        #pragma unroll
        for (int j = 0; j < 4; ++j) {
            u16x8 v = *(const u16x8*)(opc + j * 8);
            #pragma unroll
            for (int e = 0; e < 8; ++e)
                acc[j * 8 + e] += bf2f(v[e]) * wgt;
        }
    }
    const float inv = 1.f / l_fin;

    #pragma unroll
    for (int j = 0; j < 4; ++j) {
        u16x8 ov;
        #pragma unroll
        for (int e = 0; e < 8; ++e) ov[e] = cvt_bf16(acc[j * 8 + e] * inv);
        *(u16x8*)&Os[row][seg + j * 8] = ov;
    }
    __syncthreads();

    // Y = O @ Wp
    const int w = t >> 6;
    const int lane = t & 63;
    const int lr = lane & 15;
    const int lg = lane >> 4;
    u16x8 af[4];
    #pragma unroll
    for (int dk = 0; dk < 4; ++dk)
        af[dk] = *(u16x8*)&Os[16 * w + lr][dk * 32 + lg * 8];
    float* op = out + ((size_t)b * T_DIM + io * 64) * D_DIM;
    #pragma unroll
    for (int nt = 0; nt < 8; ++nt) {
        f32x4 y = f32x4{0.f, 0.f, 0.f, 0.f};
        #pragma unroll
        for (int dk = 0; dk < 4; ++dk) {
            u16x8 bv = *(const u16x8*)&Wpt[(size_t)(nt * 16 + lr) * D_DIM + dk * 32 + lg * 8];
            y = mfma16(af[dk], bv, y);
        }
        #pragma unroll
        for (int r = 0; r < 4; ++r)
            op[(size_t)(16 * w + 4 * lg + r) * D_DIM + nt * 16 + lr] = y[r];
    }
}

extern "C" void kernel_launch(void* const* d_in, const int* in_sizes, int n_in,
                              void* d_out, int out_size, void* d_ws, size_t ws_size,
                              hipStream_t stream) {
    const float* x  = (const float*)d_in[0];
    const float* Wk = (const float*)d_in[1];
    const float* Wq = (const float*)d_in[2];
    const float* Wv = (const float*)d_in[3];
    const float* Wp = (const float*)d_in[4];
    float* out = (float*)d_out;

    char* ws = (char*)d_ws;
    u16* qb  = (u16*)(ws);                          // 4 MB
    u16* kb  = (u16*)(ws + 4194304);                // 4 MB
    u16* vT  = (u16*)(ws + 8388608);                // 4 MB, [b][d][t]
    u16* Wqt = (u16*)(ws + 12582912);               // 256 KB
    u16* Wkt = (u16*)(ws + 12582912 + 262144);
    u16* Wvt = (u16*)(ws + 12582912 + 524288);
    u16* Wpt = (u16*)(ws + 12582912 + 786432);      // 32 KB
    float* ml   = (float*)(ws + 13631488);          // <= 576 KB
    u16* Opart  = (u16*)(ws + 14680064);            // <= 18.9 MB

    const bool big = ws_size >= (size_t)36 * 1024 * 1024;
    const int SPLIT = big ? 1 : 0;
    const int GX = big ? 144 : 32;                  // 144 = 4 * 8*9/2

    prep_kernel<<<1600, 256, 0, stream>>>(Wk, Wq, Wv, Wp, Wqt, Wkt, Wvt, Wpt);
    qkv_kernel<<<512, 256, 0, stream>>>(x, Wqt, Wkt, Wvt, qb, kb, vT);
    attn_kernel<<<dim3(GX, 4), 512, 0, stream>>>(qb, kb, vT, Opart, ml, SPLIT);
    combine_kernel<<<dim3(64, 4), 256, 0, stream>>>(Opart, ml, Wpt, out, SPLIT, GX);
}

// Round 11
// 94.740 us; speedup vs baseline: 1.1396x; 1.1396x over previous
//
#include <hip/hip_runtime.h>

#define E_DIM 1024
#define D_DIM 128
#define T_DIM 4096

typedef unsigned short u16;
typedef u16 u16x8 __attribute__((ext_vector_type(8)));
typedef u16 u16x4 __attribute__((ext_vector_type(4)));
typedef __bf16 bf16x8 __attribute__((ext_vector_type(8)));
typedef float f32x4 __attribute__((ext_vector_type(4)));

__device__ __forceinline__ u16 cvt_bf16(float f) {
    unsigned u = __float_as_uint(f);
    u += 0x7FFF + ((u >> 16) & 1);   // RNE
    return (u16)(u >> 16);
}

__device__ __forceinline__ float bf2f(u16 v) {
    return __uint_as_float(((unsigned)v) << 16);
}

__device__ __forceinline__ f32x4 mfma16(u16x8 a, u16x8 b, f32x4 c) {
    return __builtin_amdgcn_mfma_f32_16x16x32_bf16(
        __builtin_bit_cast(bf16x8, a), __builtin_bit_cast(bf16x8, b), c, 0, 0, 0);
}

// async global->LDS DMA, 16B per lane; lds ptr must be wave-uniform base
__device__ __forceinline__ void gld_lds16(const void* g, void* l) {
    __builtin_amdgcn_global_load_lds(
        (const __attribute__((address_space(1))) unsigned int*)g,
        (__attribute__((address_space(3))) unsigned int*)l, 16, 0, 0);
}

// ---------- prep: transpose weights to [out][in], cast to bf16 ----------
__global__ void prep_kernel(const float* __restrict__ Wk, const float* __restrict__ Wq,
                            const float* __restrict__ Wv, const float* __restrict__ Wp,
                            u16* __restrict__ Wqt, u16* __restrict__ Wkt,
                            u16* __restrict__ Wvt, u16* __restrict__ Wpt) {
    int tid = blockIdx.x * 256 + threadIdx.x;
    const int WT = 128 * 1024;
    if (tid < 3 * WT) {
        int w = tid / WT;
        int r = tid - w * WT;
        int n = r >> 10, k = r & 1023;
        const float* W = (w == 0) ? Wq : (w == 1) ? Wk : Wv;
        u16* Wt = (w == 0) ? Wqt : (w == 1) ? Wkt : Wvt;
        Wt[r] = cvt_bf16(W[k * 128 + n]);
    } else {
        int r = tid - 3 * WT;
        if (r < 128 * 128) {
            int n = r >> 7, k = r & 127;
            Wpt[r] = cvt_bf16(Wp[k * 128 + n]);
        }
    }
}

// ---------- fused QKV projection v4: 2-iteration-deep counted-vmcnt pipeline ----------
// 256 blocks x 512 threads: 64 rows x 384 cols. Wave w: 16-row sub-tile (w&3),
// 192-col half (w>>2). W in 4 LDS buffers (4 x 24576 B), staged 2 k-tiles ahead
// via gld_lds with slot rotation (conflict-free). x per-lane global->reg,
// 2 tiles ahead (xa/xb parity). Per iter: 5 VMEM issued, vmcnt(5) at end.
__global__ __launch_bounds__(512) void qkv_kernel(
        const float* __restrict__ x,
        const u16* __restrict__ Wqt, const u16* __restrict__ Wkt, const u16* __restrict__ Wvt,
        u16* __restrict__ qb, u16* __restrict__ kb, u16* __restrict__ vT) {
    __shared__ __align__(16) char smem[98304];   // 4 x 24576 (384 rows x 64B each)

    const int t = threadIdx.x;
    const int w = t >> 6;
    const int lane = t & 63;
    const int lr = lane & 15;
    const int lg = lane >> 4;
    const int m4 = w & 3;          // 16-row sub-tile
    const int n2 = w >> 2;         // 192-col half
    const int r0 = blockIdx.x * 64;

    // stage 384x32 W tile (K0) into buffer BUF; LDS (row,slot x) holds source
    // k-slot s=(x-(row>>1))&3 -> read addr slot = (lg+(row>>1))&3 (conflict-free)
    #define STAGE_W(K0, BUF) do {                                                 \
        char* wB_ = smem + (BUF) * 24576;                                         \
        _Pragma("unroll")                                                         \
        for (int c2 = 0; c2 < 3; ++c2) {                                          \
            const int rl_ = c2 * 128 + (t >> 2);                                  \
            const u16* W_ = (rl_ < 128) ? Wqt : (rl_ < 256) ? Wkt : Wvt;          \
            const int s_ = ((t & 3) - (rl_ >> 1)) & 3;                            \
            gld_lds16(W_ + (size_t)(rl_ & 127) * E_DIM + (K0) + 8 * s_,           \
                      wB_ + c2 * 8192 + t * 16);                                  \
        }                                                                         \
    } while (0)

    const float* xp = x + (size_t)(r0 + 16 * m4 + lr) * E_DIM + lg * 8;

    float4 xa[2], xb[2];
    #define XLOAD(arr, K0) do {                                                   \
        arr[0] = *(const float4*)(xp + (K0));                                     \
        arr[1] = *(const float4*)(xp + (K0) + 4);                                 \
    } while (0)

    #define CVT_AV(av, arr) do {                                                  \
        av[0] = cvt_bf16(arr[0].x); av[1] = cvt_bf16(arr[0].y);                   \
        av[2] = cvt_bf16(arr[0].z); av[3] = cvt_bf16(arr[0].w);                   \
        av[4] = cvt_bf16(arr[1].x); av[5] = cvt_bf16(arr[1].y);                   \
        av[6] = cvt_bf16(arr[1].z); av[7] = cvt_bf16(arr[1].w);                   \
    } while (0)

    f32x4 acc[12];
    #pragma unroll
    for (int j = 0; j < 12; ++j) acc[j] = f32x4{0.f, 0.f, 0.f, 0.f};

    // one iteration: cvt x_kk -> issue W/x for kk+2 -> 12 MFMA from buf kk&3 ->
    // vmcnt(5): drain kk+1's set (issued a full iter ago), keep kk+2's in flight
    #define ITER(KK, XARR) do {                                                   \
        const int kk_ = (KK);                                                     \
        u16x8 av_;                                                                \
        CVT_AV(av_, XARR);                                                        \
        __builtin_amdgcn_sched_barrier(0);                                        \
        if (kk_ < 30) {                                                           \
            STAGE_W(kk_ * 32 + 64, (kk_ + 2) & 3);                                \
            __builtin_amdgcn_sched_barrier(0);                                    \
            XLOAD(XARR, kk_ * 32 + 64);                                           \
        }                                                                         \
        __builtin_amdgcn_sched_barrier(0);                                        \
        {                                                                         \
            char* wB = smem + ((kk_) & 3) * 24576;                                \
            __builtin_amdgcn_s_setprio(1);                                        \
            _Pragma("unroll")                                                     \
            for (int nt = 0; nt < 12; ++nt) {                                     \
                const int ln = n2 * 192 + nt * 16 + lr;                           \
                u16x8 bv = *(u16x8*)(wB + ln * 64 + (((lg + (ln >> 1)) & 3) << 4)); \
                acc[nt] = mfma16(av_, bv, acc[nt]);                               \
            }                                                                     \
            __builtin_amdgcn_s_setprio(0);                                        \
        }                                                                         \
        if (kk_ < 30) asm volatile("s_waitcnt vmcnt(5)" ::: "memory");            \
        else          asm volatile("s_waitcnt vmcnt(0)" ::: "memory");            \
        __builtin_amdgcn_s_barrier();                                             \
    } while (0)

    // prologue: tiles 0 and 1 in flight (order: W0,x0,W1,x1), drain set 0
    STAGE_W(0, 0);
    XLOAD(xa, 0);
    STAGE_W(32, 1);
    XLOAD(xb, 32);
    asm volatile("s_waitcnt vmcnt(5)" ::: "memory");
    __builtin_amdgcn_s_barrier();

    for (int kk2 = 0; kk2 < 16; ++kk2) {
        ITER(2 * kk2, xa);
        ITER(2 * kk2 + 1, xb);
    }
    #undef STAGE_W
    #undef XLOAD
    #undef CVT_AV
    #undef ITER

    // epilogue: D layout col=lane&15, row=4*(lane>>4)+reg
    const int bb = r0 >> 12;
    const int row0 = r0 + 16 * m4 + 4 * lg;
    const int tt0 = row0 & 4095;
    #pragma unroll
    for (int nt = 0; nt < 12; ++nt) {
        const int col_g = n2 * 192 + nt * 16 + lr;
        const int j = col_g >> 7;
        const int colw = col_g & 127;
        if (j < 2) {
            u16* outb = (j == 0) ? qb : kb;
            #pragma unroll
            for (int reg = 0; reg < 4; ++reg)
                outb[(size_t)(row0 + reg) * D_DIM + colw] = cvt_bf16(acc[nt][reg]);
        } else {
            u16x4 pv;
            #pragma unroll
            for (int reg = 0; reg < 4; ++reg) pv[reg] = cvt_bf16(acc[nt][reg]);
            *(u16x4*)&vT[((size_t)(bb * 128 + colw)) * T_DIM + tt0] = pv;
        }
    }
}

// ---------- flash attention (causal): QBLK=128, 8 waves, K/V LDS dbuf, O^T accum ----------
__global__ __launch_bounds__(512) void attn_kernel(
        const u16* __restrict__ qb, const u16* __restrict__ kb, const u16* __restrict__ vT,
        u16* __restrict__ Opart, float* __restrict__ ml, int SPLIT) {
    const int g = blockIdx.x;
    const int b = blockIdx.y;
    int i, c;
    if (SPLIT) {
        int k = 0;
        while (2 * (k + 1) * (k + 2) <= g) ++k;
        const int off = g - 2 * k * (k + 1);
        const int iband = off / (k + 1);
        c = off - iband * (k + 1);
        i = 4 * k + iband;
    } else { i = g; c = 0; }

    const int q0 = i * 128;
    const int kv_beg = c * 512;
    const int kv_end = SPLIT ? min(q0 + 128, kv_beg + 512) : (q0 + 128);
    const int slot = b * gridDim.x + g;

    __shared__ __align__(16) char smem[81920];

    const int t = threadIdx.x;
    const int w = t >> 6;          // 0..7
    const int lane = t & 63;
    const int lr = lane & 15;
    const int lg = lane >> 4;
    const size_t base = (size_t)b * T_DIM * D_DIM;

    // Q fragments direct from global (L2-resident)
    u16x8 qf[4];
    {
        const u16* qp = qb + base + (size_t)(q0 + 16 * w + lr) * D_DIM + lg * 8;
        #pragma unroll
        for (int dk = 0; dk < 4; ++dk) qf[dk] = *(const u16x8*)(qp + dk * 32);
    }

    const char* kpb = (const char*)(kb + base);
    const char* vpb = (const char*)(vT + (size_t)b * D_DIM * T_DIM);
    const int key = (lr & 7) << 4;

    #define STAGE(S0, BUF) do {                                                   \
        char* kB_ = smem + (BUF) * 16384;                                         \
        char* vB_ = smem + 32768 + (BUF) * 16384;                                 \
        const int wbase_ = (t >> 6) * 1024;                                       \
        _Pragma("unroll")                                                         \
        for (int c2 = 0; c2 < 2; ++c2) {                                          \
            const int krow_ = c2 * 32 + (t >> 4);                                 \
            gld_lds16(kpb + (size_t)((S0) + krow_) * 256 +                        \
                      (((t & 15) * 16) ^ ((krow_ & 7) * 16)),                     \
                      kB_ + c2 * 8192 + wbase_);                                  \
            const int vrow_ = c2 * 64 + (t >> 3);                                 \
            gld_lds16(vpb + (size_t)vrow_ * (T_DIM * 2) + (size_t)(S0) * 2 +      \
                      (((t & 7) * 16) ^ ((vrow_ & 7) * 16)),                      \
                      vB_ + c2 * 8192 + wbase_);                                  \
        }                                                                         \
    } while (0)

    f32x4 oacc[8];
    #pragma unroll
    for (int nn = 0; nn < 8; ++nn) oacc[nn] = f32x4{0.f, 0.f, 0.f, 0.f};
    float m_run = -1e30f, l_run = 0.f;
    const float scale2 = 0.12752048520120164f;  // log2(e)/sqrt(128)
    const int qrow = q0 + 16 * w + lr;          // this lane's q row

    STAGE(kv_beg, 0);
    asm volatile("s_waitcnt vmcnt(0)" ::: "memory");
    __syncthreads();

    int buf = 0;
    for (int s0 = kv_beg; s0 < kv_end; s0 += 64) {
        if (s0 + 64 < kv_end) STAGE(s0 + 64, buf ^ 1);   // async prefetch

        char* kB  = smem + buf * 16384;
        char* vB  = smem + 32768 + buf * 16384;
        char* psB = smem + 65536 + w * 2048;

        // S^T = K Q^T : lane (lr,lg) holds S[s=s0+16nt+4lg+r][q=16w+lr]
        f32x4 sacc[4];
        #pragma unroll
        for (int nn = 0; nn < 4; ++nn) sacc[nn] = f32x4{0.f, 0.f, 0.f, 0.f};
        __builtin_amdgcn_s_setprio(1);
        #pragma unroll
        for (int dk = 0; dk < 4; ++dk) {
            #pragma unroll
            for (int nt = 0; nt < 4; ++nt) {
                u16x8 kfr = *(u16x8*)(kB + (nt * 16 + lr) * 256 + ((dk * 64 + lg * 16) ^ key));
                sacc[nt] = mfma16(kfr, qf[dk], sacc[nt]);
            }
        }
        __builtin_amdgcn_s_setprio(0);

        // scale + causal mask
        float sv[4][4];
        const bool need_mask = (s0 + 63 > q0 + 16 * w);
        #pragma unroll
        for (int nt = 0; nt < 4; ++nt) {
            #pragma unroll
            for (int r = 0; r < 4; ++r) {
                float v = sacc[nt][r] * scale2;
                if (need_mask && (s0 + nt * 16 + 4 * lg + r) > qrow) v = -1e30f;
                sv[nt][r] = v;
            }
        }

        // softmax: in-register over 16 + 2-level cross-lg reduce (lane-local row)
        float tmax = sv[0][0];
        #pragma unroll
        for (int nt = 0; nt < 4; ++nt)
            #pragma unroll
            for (int r = 0; r < 4; ++r) tmax = fmaxf(tmax, sv[nt][r]);
        tmax = fmaxf(tmax, __shfl_xor(tmax, 16));
        tmax = fmaxf(tmax, __shfl_xor(tmax, 32));
        float m_new = fmaxf(m_run, tmax);
        float rsc = __builtin_amdgcn_exp2f(m_run - m_new);
        m_run = m_new;
        float tsum = 0.f;
        #pragma unroll
        for (int nt = 0; nt < 4; ++nt)
            #pragma unroll
            for (int r = 0; r < 4; ++r) {
                sv[nt][r] = __builtin_amdgcn_exp2f(sv[nt][r] - m_new);
                tsum += sv[nt][r];
            }
        tsum += __shfl_xor(tsum, 16);
        tsum += __shfl_xor(tsum, 32);
        l_run = l_run * rsc + tsum;

        // rescale O^T accumulator: factor lane-local (output col q = lr)
        #pragma unroll
        for (int nt = 0; nt < 8; ++nt)
            #pragma unroll
            for (int r = 0; r < 4; ++r) oacc[nt][r] *= rsc;

        // P -> wave-private swizzled Ps: lane writes row q=lr, cols 16nt+4lg+{0..3}
        #pragma unroll
        for (int nt = 0; nt < 4; ++nt) {
            u16x4 pv4;
            #pragma unroll
            for (int r = 0; r < 4; ++r) pv4[r] = cvt_bf16(sv[nt][r]);
            *(u16x4*)(psB + lr * 128 + ((nt * 32 + lg * 8) ^ key)) = pv4;
        }

        // P^T fragments: lane (lr,lg) reads P[q=lr][s=8lg+e] (+32)
        u16x8 pA0 = *(u16x8*)(psB + lr * 128 + ((lg * 16) ^ key));
        u16x8 pA1 = *(u16x8*)(psB + lr * 128 + ((64 + lg * 16) ^ key));

        // O^T += V^T P^T  (A = V^T fragment from LDS, B = P^T fragment)
        __builtin_amdgcn_s_setprio(1);
        #pragma unroll
        for (int nt = 0; nt < 8; ++nt) {
            u16x8 bv0 = *(u16x8*)(vB + (nt * 16 + lr) * 128 + ((lg * 16) ^ key));
            oacc[nt] = mfma16(bv0, pA0, oacc[nt]);
            u16x8 bv1 = *(u16x8*)(vB + (nt * 16 + lr) * 128 + ((64 + lg * 16) ^ key));
            oacc[nt] = mfma16(bv1, pA1, oacc[nt]);
        }
        __builtin_amdgcn_s_setprio(0);

        asm volatile("s_waitcnt vmcnt(0)" ::: "memory");   // drain prefetch
        __syncthreads();
        buf ^= 1;
    }
    #undef STAGE

    // m,l per q row (lane lr of lg==0 owns q=16w+lr)
    if (lg == 0) {
        int row = 16 * w + lr;
        ml[(size_t)(slot * 128 + row) * 2]     = m_run;
        ml[(size_t)(slot * 128 + row) * 2 + 1] = l_run;
    }

    // normalize (lane-local) and bounce O through LDS (reuse Kbuf, 128x256B swz)
    const float invl = 1.f / l_run;
    const int orw = 16 * w + lr;
    #pragma unroll
    for (int nt = 0; nt < 8; ++nt) {
        u16x4 ov;
        #pragma unroll
        for (int r = 0; r < 4; ++r) ov[r] = cvt_bf16(oacc[nt][r] * invl);
        *(u16x4*)(smem + orw * 256 + ((32 * nt + 8 * lg) ^ ((orw & 7) << 4))) = ov;
    }
    __syncthreads();
    u16* op = Opart + (size_t)slot * 16384;
    const int orow = t >> 2;
    const int oseg = t & 3;
    #pragma unroll
    for (int j = 0; j < 4; ++j) {
        u16x8 vv = *(u16x8*)(smem + orow * 256 + ((oseg * 64 + j * 16) ^ ((orow & 7) << 4)));
        *(u16x8*)(op + orow * 128 + oseg * 32 + j * 8) = vv;
    }
}

// ---------- combine partials + fused output projection ----------
__global__ __launch_bounds__(256) void combine_kernel(
        const u16* __restrict__ Opart, const float* __restrict__ ml,
        const u16* __restrict__ Wpt, float* __restrict__ out,
        int SPLIT, int NSLOT) {
    const int io = blockIdx.x;          // 64-row output tile, 0..63
    const int b = blockIdx.y;
    const int i = io >> 1;              // 128-row attn tile
    const int half = io & 1;
    int NC, g0;
    if (SPLIT) {
        int k = i >> 2;
        NC = k + 1;
        g0 = 2 * k * (k + 1) + (i & 3) * (k + 1);
    } else { NC = 1; g0 = i; }
    const int slot0 = b * NSLOT + g0;

    __shared__ u16 Os[64][136];
    const int t = threadIdx.x;
    const int row = t >> 2, seg = (t & 3) * 32;
    const int row_in = half * 64 + row;

    float m_fin = -1e30f;
    for (int c = 0; c < NC; ++c)
        m_fin = fmaxf(m_fin, ml[(size_t)((slot0 + c) * 128 + row_in) * 2]);

    float acc[32];
    #pragma unroll
    for (int j = 0; j < 32; ++j) acc[j] = 0.f;
    float l_fin = 0.f;
    for (int c = 0; c < NC; ++c) {
        float mcv = ml[(size_t)((slot0 + c) * 128 + row_in) * 2];
        float lcv = ml[(size_t)((slot0 + c) * 128 + row_in) * 2 + 1];
        float wgt = __builtin_amdgcn_exp2f(mcv - m_fin) * lcv;
        l_fin += wgt;
        const u16* opc = Opart + (size_t)(slot0 + c) * 16384 + row_in * 128 + seg;
        #pragma unroll
        for (int j = 0; j < 4; ++j) {
            u16x8 v = *(const u16x8*)(opc + j * 8);
            #pragma unroll
            for (int e = 0; e < 8; ++e)
                acc[j * 8 + e] += bf2f(v[e]) * wgt;
        }
    }
    const float inv = 1.f / l_fin;

    #pragma unroll
    for (int j = 0; j < 4; ++j) {
        u16x8 ov;
        #pragma unroll
        for (int e = 0; e < 8; ++e) ov[e] = cvt_bf16(acc[j * 8 + e] * inv);
        *(u16x8*)&Os[row][seg + j * 8] = ov;
    }
    __syncthreads();

    // Y = O @ Wp
    const int w = t >> 6;
    const int lane = t & 63;
    const int lr = lane & 15;
    const int lg = lane >> 4;
    u16x8 af[4];
    #pragma unroll
    for (int dk = 0; dk < 4; ++dk)
        af[dk] = *(u16x8*)&Os[16 * w + lr][dk * 32 + lg * 8];
    float* op = out + ((size_t)b * T_DIM + io * 64) * D_DIM;
    #pragma unroll
    for (int nt = 0; nt < 8; ++nt) {
        f32x4 y = f32x4{0.f, 0.f, 0.f, 0.f};
        #pragma unroll
        for (int dk = 0; dk < 4; ++dk) {
            u16x8 bv = *(const u16x8*)&Wpt[(size_t)(nt * 16 + lr) * D_DIM + dk * 32 + lg * 8];
            y = mfma16(af[dk], bv, y);
        }
        #pragma unroll
        for (int r = 0; r < 4; ++r)
            op[(size_t)(16 * w + 4 * lg + r) * D_DIM + nt * 16 + lr] = y[r];
    }
}

extern "C" void kernel_launch(void* const* d_in, const int* in_sizes, int n_in,
                              void* d_out, int out_size, void* d_ws, size_t ws_size,
                              hipStream_t stream) {
    const float* x  = (const float*)d_in[0];
    const float* Wk = (const float*)d_in[1];
    const float* Wq = (const float*)d_in[2];
    const float* Wv = (const float*)d_in[3];
    const float* Wp = (const float*)d_in[4];
    float* out = (float*)d_out;

    char* ws = (char*)d_ws;
    u16* qb  = (u16*)(ws);                          // 4 MB
    u16* kb  = (u16*)(ws + 4194304);                // 4 MB
    u16* vT  = (u16*)(ws + 8388608);                // 4 MB, [b][d][t]
    u16* Wqt = (u16*)(ws + 12582912);               // 256 KB
    u16* Wkt = (u16*)(ws + 12582912 + 262144);
    u16* Wvt = (u16*)(ws + 12582912 + 524288);
    u16* Wpt = (u16*)(ws + 12582912 + 786432);      // 32 KB
    float* ml   = (float*)(ws + 13631488);          // <= 576 KB
    u16* Opart  = (u16*)(ws + 14680064);            // <= 18.9 MB

    const bool big = ws_size >= (size_t)36 * 1024 * 1024;
    const int SPLIT = big ? 1 : 0;
    const int GX = big ? 144 : 32;                  // 144 = 4 * 8*9/2

    prep_kernel<<<1600, 256, 0, stream>>>(Wk, Wq, Wv, Wp, Wqt, Wkt, Wvt, Wpt);
    qkv_kernel<<<256, 512, 0, stream>>>(x, Wqt, Wkt, Wvt, qb, kb, vT);
    attn_kernel<<<dim3(GX, 4), 512, 0, stream>>>(qb, kb, vT, Opart, ml, SPLIT);
    combine_kernel<<<dim3(64, 4), 256, 0, stream>>>(Opart, ml, Wpt, out, SPLIT, GX);
}